// Round 3
// baseline (856.152 us; speedup 1.0000x reference)
//
#include <hip/hip_runtime.h>

#define D_IN 128
#define D_HID 96
#define D_OUT 64

// ---------- degree count (int atomics on 50K counters — cheap) ----------
__global__ void deg_kernel(const int* __restrict__ dst, int* __restrict__ deg, int E) {
    int e = blockIdx.x * blockDim.x + threadIdx.x;
    if (e < E) atomicAdd(&deg[dst[e]], 1);
}

// ---------- single-block scan: shfl wave-scan, 4 elems/thread (3 barriers / 4096 chunk) ----------
__global__ void scan_kernel(const int* __restrict__ deg, int* __restrict__ row_ptr,
                            int* __restrict__ cursor, float* __restrict__ dinv, int n) {
    __shared__ int wsum[16];
    __shared__ int s_carry;
    const int tid = threadIdx.x;
    const int lane = tid & 63, wid = tid >> 6;
    if (tid == 0) s_carry = 0;
    __syncthreads();
    for (int base = 0; base < n; base += 4096) {
        int i0 = base + tid * 4;
        int v0 = (i0 + 0 < n) ? deg[i0 + 0] : 0;
        int v1 = (i0 + 1 < n) ? deg[i0 + 1] : 0;
        int v2 = (i0 + 2 < n) ? deg[i0 + 2] : 0;
        int v3 = (i0 + 3 < n) ? deg[i0 + 3] : 0;
        int p0 = v0, p1 = p0 + v1, p2 = p1 + v2, p3 = p2 + v3;
        int tsum = p3;                         // thread total → wave inclusive scan
        for (int off = 1; off < 64; off <<= 1) {
            int t = __shfl_up(tsum, off);
            if (lane >= off) tsum += t;
        }
        if (lane == 63) wsum[wid] = tsum;
        __syncthreads();
        if (wid == 0) {                        // inclusive scan of 16 wave sums
            int w = (lane < 16) ? wsum[lane] : 0;
            for (int off = 1; off < 16; off <<= 1) {
                int t = __shfl_up(w, off);
                if (lane >= off) w += t;
            }
            if (lane < 16) wsum[lane] = w;
        }
        __syncthreads();
        int texcl = s_carry + (wid ? wsum[wid - 1] : 0) + tsum - p3;
        int e0 = texcl, e1 = texcl + p0, e2 = texcl + p1, e3 = texcl + p2;
        if (i0 + 0 < n) { row_ptr[i0+0] = e0; cursor[i0+0] = e0; dinv[i0+0] = rsqrtf((float)v0 + 1.0f); }
        if (i0 + 1 < n) { row_ptr[i0+1] = e1; cursor[i0+1] = e1; dinv[i0+1] = rsqrtf((float)v1 + 1.0f); }
        if (i0 + 2 < n) { row_ptr[i0+2] = e2; cursor[i0+2] = e2; dinv[i0+2] = rsqrtf((float)v2 + 1.0f); }
        if (i0 + 3 < n) { row_ptr[i0+3] = e3; cursor[i0+3] = e3; dinv[i0+3] = rsqrtf((float)v3 + 1.0f); }
        __syncthreads();
        if (tid == 0) s_carry += wsum[15];
        __syncthreads();
    }
}

// ---------- bucket src indices by dst (counting sort body) ----------
__global__ void fill_kernel(const int* __restrict__ src, const int* __restrict__ dst,
                            int* __restrict__ cursor, int* __restrict__ srcIdx, int E) {
    int e = blockIdx.x * blockDim.x + threadIdx.x;
    if (e >= E) return;
    int d = dst[e];
    int pos = atomicAdd(&cursor[d], 1);
    srcIdx[pos] = src[e];
}

// ---------- tiled GEMM: H[row,:] = (X[row,:] @ W) * dinv[row] ----------
// block: (C/4, BM/4) threads; per-thread 4 rows x 4 cols register tile.
// W k-tile + X tile staged in LDS; W read once per block.
template <int K, int KT, int C, int BM>
__global__ void gemm_tiled_kernel(const float* __restrict__ X, const float* __restrict__ W,
                                  const float* __restrict__ dinv, float* __restrict__ H, int n) {
    constexpr int TX = C / 4;      // col-quads
    constexpr int TY = BM / 4;     // row-groups
    constexpr int NTH = TX * TY;
    __shared__ float Wl[KT][C];
    __shared__ float Xl[BM][KT + 1];

    const int tx = threadIdx.x, ty = threadIdx.y;
    const int tlin = ty * TX + tx;
    const int r0 = blockIdx.x * BM;
    const int row0 = ty * 4;

    float4 acc0 = {0,0,0,0}, acc1 = {0,0,0,0}, acc2 = {0,0,0,0}, acc3 = {0,0,0,0};

    for (int kt0 = 0; kt0 < K; kt0 += KT) {
        // stage W k-tile
        for (int q = tlin; q < KT * (C / 4); q += NTH) {
            int k = q / (C / 4), cq = q % (C / 4);
            *(float4*)&Wl[k][cq * 4] = *(const float4*)&W[(long)(kt0 + k) * C + cq * 4];
        }
        // stage X tile (row-clamped for tail block)
        for (int q = tlin; q < BM * (KT / 4); q += NTH) {
            int r = q / (KT / 4), kq = q % (KT / 4);
            int gr = r0 + r; if (gr >= n) gr = n - 1;
            *(float4*)&Xl[r][kq * 4] = *(const float4*)&X[(long)gr * K + kt0 + kq * 4];
        }
        __syncthreads();
#pragma unroll
        for (int k = 0; k < KT; ++k) {
            float4 w = *(const float4*)&Wl[k][tx * 4];
            float x0 = Xl[row0 + 0][k];
            float x1 = Xl[row0 + 1][k];
            float x2 = Xl[row0 + 2][k];
            float x3 = Xl[row0 + 3][k];
            acc0.x = fmaf(x0, w.x, acc0.x); acc0.y = fmaf(x0, w.y, acc0.y);
            acc0.z = fmaf(x0, w.z, acc0.z); acc0.w = fmaf(x0, w.w, acc0.w);
            acc1.x = fmaf(x1, w.x, acc1.x); acc1.y = fmaf(x1, w.y, acc1.y);
            acc1.z = fmaf(x1, w.z, acc1.z); acc1.w = fmaf(x1, w.w, acc1.w);
            acc2.x = fmaf(x2, w.x, acc2.x); acc2.y = fmaf(x2, w.y, acc2.y);
            acc2.z = fmaf(x2, w.z, acc2.z); acc2.w = fmaf(x2, w.w, acc2.w);
            acc3.x = fmaf(x3, w.x, acc3.x); acc3.y = fmaf(x3, w.y, acc3.y);
            acc3.z = fmaf(x3, w.z, acc3.z); acc3.w = fmaf(x3, w.w, acc3.w);
        }
        __syncthreads();
    }

    // epilogue: scale by dinv[row], store float4
    float4 a[4] = {acc0, acc1, acc2, acc3};
#pragma unroll
    for (int i = 0; i < 4; ++i) {
        int row = r0 + row0 + i;
        if (row < n) {
            float di = dinv[row];
            float4 o = {a[i].x * di, a[i].y * di, a[i].z * di, a[i].w * di};
            *(float4*)&H[(long)row * C + tx * 4] = o;
        }
    }
}

// ---------- out[d,:] = relu(dinv[d] * (sum_{s in N(d)} hs[s,:] + hs[d,:]) + b) ----------
template <int C, int NY>
__global__ void agg_kernel(const int* __restrict__ row_ptr, const int* __restrict__ deg,
                           const int* __restrict__ srcIdx, const float* __restrict__ hs,
                           const float* __restrict__ dinv, const float* __restrict__ b,
                           float* __restrict__ out, int n) {
    int c = threadIdx.x;                                // [0, C)
    int d = blockIdx.x * NY + threadIdx.y;
    if (d >= n) return;
    int start = row_ptr[d];
    int cnt   = deg[d];
    float acc = hs[(long)d * C + c];                    // self-loop term
    int k = 0;
    for (; k + 1 < cnt; k += 2) {                       // 2 independent gathers/iter
        int s0 = srcIdx[start + k];
        int s1 = srcIdx[start + k + 1];
        acc += hs[(long)s0 * C + c];
        acc += hs[(long)s1 * C + c];
    }
    if (k < cnt) acc += hs[(long)srcIdx[start + k] * C + c];
    out[(long)d * C + c] = fmaxf(fmaf(dinv[d], acc, b[c]), 0.f);
}

extern "C" void kernel_launch(void* const* d_in, const int* in_sizes, int n_in,
                              void* d_out, int out_size, void* d_ws, size_t ws_size,
                              hipStream_t stream) {
    const float* x  = (const float*)d_in[0];
    const int*   ei = (const int*)d_in[1];
    const float* W1 = (const float*)d_in[2];
    const float* b1 = (const float*)d_in[3];
    const float* W2 = (const float*)d_in[4];
    const float* b2 = (const float*)d_in[5];
    float* out = (float*)d_out;

    const int n = in_sizes[0] / D_IN;       // 50000
    const int E = in_sizes[1] / 2;          // 800000
    const int* srcp = ei;                   // edge_index[0]
    const int* dstp = ei + E;               // edge_index[1]

    char* ws = (char*)d_ws;
    float* dinv   = (float*)(ws);                        // n f32      (256 KB slot)
    int*   deg    = (int*)  (ws + (256u << 10));         // n int
    int*   rowp   = (int*)  (ws + (512u << 10));         // n int
    int*   cursor = (int*)  (ws + (768u << 10));         // n int
    int*   srcIdx = (int*)  (ws + (1u << 20));           // E int      (4 MB slot)
    float* h1s    = (float*)(ws + (5u << 20));           // n*96 f32   (20 MB slot)
    float* act1   = (float*)(ws + (25u << 20));          // n*96 f32   (20 MB slot)
    float* g2s    = h1s;                                 // n*64 f32 — reuses h1s (dead by then)

    hipMemsetAsync(deg, 0, (size_t)n * sizeof(int), stream);

    // CSR build
    deg_kernel<<<(E + 255) / 256, 256, 0, stream>>>(dstp, deg, E);
    scan_kernel<<<1, 1024, 0, stream>>>(deg, rowp, cursor, dinv, n);
    fill_kernel<<<(E + 255) / 256, 256, 0, stream>>>(srcp, dstp, cursor, srcIdx, E);

    const int BM = 64;
    const int nblk = (n + BM - 1) / BM;

    // layer 1: h1s = (x @ W1) * dinv ; act1 = relu(dinv*(gather-sum + self) + b1)
    {
        dim3 blk(D_HID / 4, BM / 4);   // (24,16) = 384 threads
        gemm_tiled_kernel<D_IN, 64, D_HID, BM><<<nblk, blk, 0, stream>>>(x, W1, dinv, h1s, n);
        dim3 ablk(D_HID, 2);
        agg_kernel<D_HID, 2><<<(n + 1) / 2, ablk, 0, stream>>>(rowp, deg, srcIdx, h1s, dinv, b1, act1, n);
    }

    // layer 2: g2s = (act1 @ W2) * dinv ; out = relu(dinv*(gather-sum + self) + b2)
    {
        dim3 blk(D_OUT / 4, BM / 4);   // (16,16) = 256 threads
        gemm_tiled_kernel<D_HID, D_HID, D_OUT, BM><<<nblk, blk, 0, stream>>>(act1, W2, dinv, g2s, n);
        dim3 ablk(D_OUT, 4);
        agg_kernel<D_OUT, 4><<<(n + 3) / 4, ablk, 0, stream>>>(rowp, deg, srcIdx, g2s, dinv, b2, out, n);
    }
}

// Round 5
// 336.324 us; speedup vs baseline: 2.5456x; 2.5456x over previous
//
#include <hip/hip_runtime.h>

#define D_IN 128
#define D_HID 96
#define D_OUT 64

// ---------- degree count (int atomics on 50K counters — cheap) ----------
__global__ void deg_kernel(const int* __restrict__ dst, int* __restrict__ deg, int E) {
    int e = blockIdx.x * blockDim.x + threadIdx.x;
    if (e < E) atomicAdd(&deg[dst[e]], 1);
}

// ---------- single-block scan: shfl wave-scan, 4 elems/thread ----------
__global__ void scan_kernel(const int* __restrict__ deg, int* __restrict__ row_ptr,
                            int* __restrict__ cursor, float* __restrict__ dinv, int n) {
    __shared__ int wsum[16];
    __shared__ int s_carry;
    const int tid = threadIdx.x;
    const int lane = tid & 63, wid = tid >> 6;
    if (tid == 0) s_carry = 0;
    __syncthreads();
    for (int base = 0; base < n; base += 4096) {
        int i0 = base + tid * 4;
        int v0 = (i0 + 0 < n) ? deg[i0 + 0] : 0;
        int v1 = (i0 + 1 < n) ? deg[i0 + 1] : 0;
        int v2 = (i0 + 2 < n) ? deg[i0 + 2] : 0;
        int v3 = (i0 + 3 < n) ? deg[i0 + 3] : 0;
        int p0 = v0, p1 = p0 + v1, p2 = p1 + v2, p3 = p2 + v3;
        int tsum = p3;
        for (int off = 1; off < 64; off <<= 1) {
            int t = __shfl_up(tsum, off);
            if (lane >= off) tsum += t;
        }
        if (lane == 63) wsum[wid] = tsum;
        __syncthreads();
        if (wid == 0) {
            int w = (lane < 16) ? wsum[lane] : 0;
            for (int off = 1; off < 16; off <<= 1) {
                int t = __shfl_up(w, off);
                if (lane >= off) w += t;
            }
            if (lane < 16) wsum[lane] = w;
        }
        __syncthreads();
        int texcl = s_carry + (wid ? wsum[wid - 1] : 0) + tsum - p3;
        int e0 = texcl, e1 = texcl + p0, e2 = texcl + p1, e3 = texcl + p2;
        if (i0 + 0 < n) { row_ptr[i0+0] = e0; cursor[i0+0] = e0; dinv[i0+0] = rsqrtf((float)v0 + 1.0f); }
        if (i0 + 1 < n) { row_ptr[i0+1] = e1; cursor[i0+1] = e1; dinv[i0+1] = rsqrtf((float)v1 + 1.0f); }
        if (i0 + 2 < n) { row_ptr[i0+2] = e2; cursor[i0+2] = e2; dinv[i0+2] = rsqrtf((float)v2 + 1.0f); }
        if (i0 + 3 < n) { row_ptr[i0+3] = e3; cursor[i0+3] = e3; dinv[i0+3] = rsqrtf((float)v3 + 1.0f); }
        __syncthreads();
        if (tid == 0) s_carry += wsum[15];
        __syncthreads();
    }
}

// ---------- bucket src indices by dst (counting sort body) ----------
__global__ void fill_kernel(const int* __restrict__ src, const int* __restrict__ dst,
                            int* __restrict__ cursor, int* __restrict__ srcIdx, int E) {
    int e = blockIdx.x * blockDim.x + threadIdx.x;
    if (e >= E) return;
    int d = dst[e];
    int pos = atomicAdd(&cursor[d], 1);
    srcIdx[pos] = src[e];
}

// ---------- tiled GEMM: H[row,:] = (X[row,:] @ W) * dinv[row] ----------
// KT=32 k-tiles, partial unroll (round-3 full unroll of KT=96 spilled:
// 712 MB FETCH / 530 MB WRITE of scratch traffic). 4x4 register tile.
template <int K, int C, int BM>
__global__ void gemm_tiled_kernel(const float* __restrict__ X, const float* __restrict__ W,
                                  const float* __restrict__ dinv, float* __restrict__ H, int n) {
    constexpr int KT = 32;
    constexpr int TX = C / 4;
    constexpr int TY = BM / 4;
    constexpr int NTH = TX * TY;
    constexpr int WS = C + 4;      // pad: keeps 16B alignment, rotates banks
    constexpr int XS = KT + 4;     // 36 floats = 144 B, 16B-aligned rows
    __shared__ float Wl[KT * WS];
    __shared__ float Xl[BM * XS];

    const int tx = threadIdx.x, ty = threadIdx.y;
    const int tlin = ty * TX + tx;
    const int r0 = blockIdx.x * BM;
    const int row0 = ty * 4;

    float4 acc0 = {0,0,0,0}, acc1 = {0,0,0,0}, acc2 = {0,0,0,0}, acc3 = {0,0,0,0};

    for (int kt0 = 0; kt0 < K; kt0 += KT) {
        // stage W k-tile (KT x C)
        for (int q = tlin; q < KT * (C / 4); q += NTH) {
            int k = q / (C / 4), cq = q % (C / 4);
            *(float4*)&Wl[k * WS + cq * 4] = *(const float4*)&W[(long)(kt0 + k) * C + cq * 4];
        }
        // stage X tile (BM x KT), row-clamped for tail block
        for (int q = tlin; q < BM * (KT / 4); q += NTH) {
            int r = q / (KT / 4), kq = q % (KT / 4);
            int gr = r0 + r; if (gr >= n) gr = n - 1;
            *(float4*)&Xl[r * XS + kq * 4] = *(const float4*)&X[(long)gr * K + kt0 + kq * 4];
        }
        __syncthreads();
#pragma unroll 4
        for (int k = 0; k < KT; ++k) {
            float4 w = *(const float4*)&Wl[k * WS + tx * 4];
            float x0 = Xl[(row0 + 0) * XS + k];
            float x1 = Xl[(row0 + 1) * XS + k];
            float x2 = Xl[(row0 + 2) * XS + k];
            float x3 = Xl[(row0 + 3) * XS + k];
            acc0.x = fmaf(x0, w.x, acc0.x); acc0.y = fmaf(x0, w.y, acc0.y);
            acc0.z = fmaf(x0, w.z, acc0.z); acc0.w = fmaf(x0, w.w, acc0.w);
            acc1.x = fmaf(x1, w.x, acc1.x); acc1.y = fmaf(x1, w.y, acc1.y);
            acc1.z = fmaf(x1, w.z, acc1.z); acc1.w = fmaf(x1, w.w, acc1.w);
            acc2.x = fmaf(x2, w.x, acc2.x); acc2.y = fmaf(x2, w.y, acc2.y);
            acc2.z = fmaf(x2, w.z, acc2.z); acc2.w = fmaf(x2, w.w, acc2.w);
            acc3.x = fmaf(x3, w.x, acc3.x); acc3.y = fmaf(x3, w.y, acc3.y);
            acc3.z = fmaf(x3, w.z, acc3.z); acc3.w = fmaf(x3, w.w, acc3.w);
        }
        __syncthreads();
    }

    float4 a[4] = {acc0, acc1, acc2, acc3};
#pragma unroll
    for (int i = 0; i < 4; ++i) {
        int row = r0 + row0 + i;
        if (row < n) {
            float di = dinv[row];
            float4 o = {a[i].x * di, a[i].y * di, a[i].z * di, a[i].w * di};
            *(float4*)&H[(long)row * C + tx * 4] = o;
        }
    }
}

// ---------- out[d,:] = relu(dinv[d]*(sum_{s in N(d)} hs[s,:] + hs[d,:]) + b) ----------
// float4 per thread: C/4 threads per row, 2-edge unrolled gather.
template <int C, int NY>
__global__ void agg4_kernel(const int* __restrict__ row_ptr, const int* __restrict__ deg,
                            const int* __restrict__ srcIdx, const float* __restrict__ hs,
                            const float* __restrict__ dinv, const float* __restrict__ b,
                            float* __restrict__ out, int n) {
    int tx = threadIdx.x;                               // [0, C/4)
    int d = blockIdx.x * NY + threadIdx.y;
    if (d >= n) return;
    int start = row_ptr[d];
    int cnt   = deg[d];
    float4 acc = *(const float4*)&hs[(long)d * C + tx * 4];   // self-loop term
    int k = 0;
    for (; k + 1 < cnt; k += 2) {
        int s0 = srcIdx[start + k];
        int s1 = srcIdx[start + k + 1];
        float4 v0 = *(const float4*)&hs[(long)s0 * C + tx * 4];
        float4 v1 = *(const float4*)&hs[(long)s1 * C + tx * 4];
        acc.x += v0.x + v1.x; acc.y += v0.y + v1.y;
        acc.z += v0.z + v1.z; acc.w += v0.w + v1.w;
    }
    if (k < cnt) {
        float4 v = *(const float4*)&hs[(long)srcIdx[start + k] * C + tx * 4];
        acc.x += v.x; acc.y += v.y; acc.z += v.z; acc.w += v.w;
    }
    float di = dinv[d];
    const float4 bb = *(const float4*)&b[tx * 4];
    float4 o;
    o.x = fmaxf(fmaf(di, acc.x, bb.x), 0.f);
    o.y = fmaxf(fmaf(di, acc.y, bb.y), 0.f);
    o.z = fmaxf(fmaf(di, acc.z, bb.z), 0.f);
    o.w = fmaxf(fmaf(di, acc.w, bb.w), 0.f);
    *(float4*)&out[(long)d * C + tx * 4] = o;
}

extern "C" void kernel_launch(void* const* d_in, const int* in_sizes, int n_in,
                              void* d_out, int out_size, void* d_ws, size_t ws_size,
                              hipStream_t stream) {
    const float* x  = (const float*)d_in[0];
    const int*   ei = (const int*)d_in[1];
    const float* W1 = (const float*)d_in[2];
    const float* b1 = (const float*)d_in[3];
    const float* W2 = (const float*)d_in[4];
    const float* b2 = (const float*)d_in[5];
    float* out = (float*)d_out;

    const int n = in_sizes[0] / D_IN;       // 50000
    const int E = in_sizes[1] / 2;          // 800000
    const int* srcp = ei;                   // edge_index[0]
    const int* dstp = ei + E;               // edge_index[1]

    char* ws = (char*)d_ws;
    float* dinv   = (float*)(ws);
    int*   deg    = (int*)  (ws + (256u << 10));
    int*   rowp   = (int*)  (ws + (512u << 10));
    int*   cursor = (int*)  (ws + (768u << 10));
    int*   srcIdx = (int*)  (ws + (1u << 20));
    float* h1s    = (float*)(ws + (5u << 20));
    float* act1   = (float*)(ws + (25u << 20));
    float* g2s    = h1s;                                 // dead by layer 2

    hipMemsetAsync(deg, 0, (size_t)n * sizeof(int), stream);

    // CSR build
    deg_kernel<<<(E + 255) / 256, 256, 0, stream>>>(dstp, deg, E);
    scan_kernel<<<1, 1024, 0, stream>>>(deg, rowp, cursor, dinv, n);
    fill_kernel<<<(E + 255) / 256, 256, 0, stream>>>(srcp, dstp, cursor, srcIdx, E);

    const int BM = 64;
    const int nblk = (n + BM - 1) / BM;

    // layer 1
    {
        dim3 blk(D_HID / 4, BM / 4);   // (24,16) = 384 threads
        gemm_tiled_kernel<D_IN, D_HID, BM><<<nblk, blk, 0, stream>>>(x, W1, dinv, h1s, n);
        dim3 ablk(D_HID / 4, 8);       // (24,8) = 192 threads
        agg4_kernel<D_HID, 8><<<(n + 7) / 8, ablk, 0, stream>>>(rowp, deg, srcIdx, h1s, dinv, b1, act1, n);
    }

    // layer 2
    {
        dim3 blk(D_OUT / 4, BM / 4);   // (16,16) = 256 threads
        gemm_tiled_kernel<D_HID, D_OUT, BM><<<nblk, blk, 0, stream>>>(act1, W2, dinv, g2s, n);
        dim3 ablk(D_OUT / 4, 16);      // (16,16) = 256 threads
        agg4_kernel<D_OUT, 16><<<(n + 15) / 16, ablk, 0, stream>>>(rowp, deg, srcIdx, g2s, dinv, b2, out, n);
    }
}

// Round 7
// 285.727 us; speedup vs baseline: 2.9964x; 1.1771x over previous
//
#include <hip/hip_runtime.h>

#define D_IN 128
#define D_HID 96
#define D_OUT 64
#define CHUNK 4096

// ---------- degree count: 4 edges/thread for atomic-latency hiding ----------
__global__ void deg_kernel(const int* __restrict__ dst, int* __restrict__ deg, int E) {
    int e0 = (blockIdx.x * blockDim.x + threadIdx.x) * 4;
    if (e0 + 3 < E) {
        int4 d = *(const int4*)&dst[e0];
        atomicAdd(&deg[d.x], 1);
        atomicAdd(&deg[d.y], 1);
        atomicAdd(&deg[d.z], 1);
        atomicAdd(&deg[d.w], 1);
    } else {
        for (int j = 0; j < 4; ++j) {
            int e = e0 + j;
            if (e < E) atomicAdd(&deg[dst[e]], 1);
        }
    }
}

// ---------- scan pass A: per-chunk sums (13 blocks x 1024 thr x 4 elems) ----------
__global__ void scanA_kernel(const int* __restrict__ deg, int* __restrict__ partial, int n) {
    __shared__ int wsum[16];
    const int tid = threadIdx.x, lane = tid & 63, wid = tid >> 6;
    int i0 = blockIdx.x * CHUNK + tid * 4;
    int s = 0;
    if (i0 + 3 < n) {
        int4 v = *(const int4*)&deg[i0];
        s = v.x + v.y + v.z + v.w;
    } else {
        for (int j = 0; j < 4; ++j) if (i0 + j < n) s += deg[i0 + j];
    }
    for (int off = 32; off; off >>= 1) s += __shfl_down(s, off);
    if (lane == 0) wsum[wid] = s;
    __syncthreads();
    if (tid == 0) {
        int t = 0;
        for (int w = 0; w < 16; ++w) t += wsum[w];
        partial[blockIdx.x] = t;
    }
}

// ---------- scan pass B: exclusive scan of <=64 chunk sums (1 wave) ----------
__global__ void scanB_kernel(const int* __restrict__ partial, int* __restrict__ offs, int nb) {
    int lane = threadIdx.x;          // 64 threads
    int v = (lane < nb) ? partial[lane] : 0;
    int s = v;
    for (int off = 1; off < 64; off <<= 1) {
        int t = __shfl_up(s, off);
        if (lane >= off) s += t;
    }
    if (lane < nb) offs[lane] = s - v;   // exclusive
}

// ---------- scan pass C: per-chunk scan + base offset; also dinv + cursor ----------
__global__ void scanC_kernel(const int* __restrict__ deg, const int* __restrict__ offs,
                             int* __restrict__ row_ptr, int* __restrict__ cursor,
                             float* __restrict__ dinv, int n) {
    __shared__ int wsum[16];
    const int tid = threadIdx.x, lane = tid & 63, wid = tid >> 6;
    const int base = offs[blockIdx.x];
    int i0 = blockIdx.x * CHUNK + tid * 4;
    int v0 = (i0 + 0 < n) ? deg[i0 + 0] : 0;
    int v1 = (i0 + 1 < n) ? deg[i0 + 1] : 0;
    int v2 = (i0 + 2 < n) ? deg[i0 + 2] : 0;
    int v3 = (i0 + 3 < n) ? deg[i0 + 3] : 0;
    int p0 = v0, p1 = p0 + v1, p2 = p1 + v2, p3 = p2 + v3;
    int tsum = p3;
    for (int off = 1; off < 64; off <<= 1) {
        int t = __shfl_up(tsum, off);
        if (lane >= off) tsum += t;
    }
    if (lane == 63) wsum[wid] = tsum;
    __syncthreads();
    if (wid == 0) {
        int w = (lane < 16) ? wsum[lane] : 0;
        for (int off = 1; off < 16; off <<= 1) {
            int t = __shfl_up(w, off);
            if (lane >= off) w += t;
        }
        if (lane < 16) wsum[lane] = w;
    }
    __syncthreads();
    int texcl = base + (wid ? wsum[wid - 1] : 0) + tsum - p3;
    int e0 = texcl, e1 = texcl + p0, e2 = texcl + p1, e3 = texcl + p2;
    if (i0 + 0 < n) { row_ptr[i0+0] = e0; cursor[i0+0] = e0; dinv[i0+0] = rsqrtf((float)v0 + 1.0f); }
    if (i0 + 1 < n) { row_ptr[i0+1] = e1; cursor[i0+1] = e1; dinv[i0+1] = rsqrtf((float)v1 + 1.0f); }
    if (i0 + 2 < n) { row_ptr[i0+2] = e2; cursor[i0+2] = e2; dinv[i0+2] = rsqrtf((float)v2 + 1.0f); }
    if (i0 + 3 < n) { row_ptr[i0+3] = e3; cursor[i0+3] = e3; dinv[i0+3] = rsqrtf((float)v3 + 1.0f); }
}

// ---------- bucket src indices by dst; 4 edges/thread, ushort payload ----------
__global__ void fill_kernel(const int* __restrict__ src, const int* __restrict__ dst,
                            int* __restrict__ cursor, unsigned short* __restrict__ srcIdx, int E) {
    int e0 = (blockIdx.x * blockDim.x + threadIdx.x) * 4;
    if (e0 + 3 < E) {
        int4 d = *(const int4*)&dst[e0];
        int4 s = *(const int4*)&src[e0];
        int p0 = atomicAdd(&cursor[d.x], 1);
        int p1 = atomicAdd(&cursor[d.y], 1);
        int p2 = atomicAdd(&cursor[d.z], 1);
        int p3 = atomicAdd(&cursor[d.w], 1);
        srcIdx[p0] = (unsigned short)s.x;
        srcIdx[p1] = (unsigned short)s.y;
        srcIdx[p2] = (unsigned short)s.z;
        srcIdx[p3] = (unsigned short)s.w;
    } else {
        for (int j = 0; j < 4; ++j) {
            int e = e0 + j;
            if (e < E) {
                int pos = atomicAdd(&cursor[dst[e]], 1);
                srcIdx[pos] = (unsigned short)src[e];
            }
        }
    }
}

// ---------- tiled GEMM: H[row,:] = (X[row,:] @ W) * dinv[row] ----------
// KT=32 k-tiles, partial unroll (full unroll of KT>=64 spilled to scratch).
template <int K, int C, int BM>
__global__ void gemm_tiled_kernel(const float* __restrict__ X, const float* __restrict__ W,
                                  const float* __restrict__ dinv, float* __restrict__ H, int n) {
    constexpr int KT = 32;
    constexpr int TX = C / 4;
    constexpr int TY = BM / 4;
    constexpr int NTH = TX * TY;
    constexpr int WS = C + 4;
    constexpr int XS = KT + 4;
    __shared__ float Wl[KT * WS];
    __shared__ float Xl[BM * XS];

    const int tx = threadIdx.x, ty = threadIdx.y;
    const int tlin = ty * TX + tx;
    const int r0 = blockIdx.x * BM;
    const int row0 = ty * 4;

    float4 acc0 = {0,0,0,0}, acc1 = {0,0,0,0}, acc2 = {0,0,0,0}, acc3 = {0,0,0,0};

    for (int kt0 = 0; kt0 < K; kt0 += KT) {
        for (int q = tlin; q < KT * (C / 4); q += NTH) {
            int k = q / (C / 4), cq = q % (C / 4);
            *(float4*)&Wl[k * WS + cq * 4] = *(const float4*)&W[(long)(kt0 + k) * C + cq * 4];
        }
        for (int q = tlin; q < BM * (KT / 4); q += NTH) {
            int r = q / (KT / 4), kq = q % (KT / 4);
            int gr = r0 + r; if (gr >= n) gr = n - 1;
            *(float4*)&Xl[r * XS + kq * 4] = *(const float4*)&X[(long)gr * K + kt0 + kq * 4];
        }
        __syncthreads();
#pragma unroll 4
        for (int k = 0; k < KT; ++k) {
            float4 w = *(const float4*)&Wl[k * WS + tx * 4];
            float x0 = Xl[(row0 + 0) * XS + k];
            float x1 = Xl[(row0 + 1) * XS + k];
            float x2 = Xl[(row0 + 2) * XS + k];
            float x3 = Xl[(row0 + 3) * XS + k];
            acc0.x = fmaf(x0, w.x, acc0.x); acc0.y = fmaf(x0, w.y, acc0.y);
            acc0.z = fmaf(x0, w.z, acc0.z); acc0.w = fmaf(x0, w.w, acc0.w);
            acc1.x = fmaf(x1, w.x, acc1.x); acc1.y = fmaf(x1, w.y, acc1.y);
            acc1.z = fmaf(x1, w.z, acc1.z); acc1.w = fmaf(x1, w.w, acc1.w);
            acc2.x = fmaf(x2, w.x, acc2.x); acc2.y = fmaf(x2, w.y, acc2.y);
            acc2.z = fmaf(x2, w.z, acc2.z); acc2.w = fmaf(x2, w.w, acc2.w);
            acc3.x = fmaf(x3, w.x, acc3.x); acc3.y = fmaf(x3, w.y, acc3.y);
            acc3.z = fmaf(x3, w.z, acc3.z); acc3.w = fmaf(x3, w.w, acc3.w);
        }
        __syncthreads();
    }

    float4 a[4] = {acc0, acc1, acc2, acc3};
#pragma unroll
    for (int i = 0; i < 4; ++i) {
        int row = r0 + row0 + i;
        if (row < n) {
            float di = dinv[row];
            float4 o = {a[i].x * di, a[i].y * di, a[i].z * di, a[i].w * di};
            *(float4*)&H[(long)row * C + tx * 4] = o;
        }
    }
}

// ---------- out[d,:] = relu(dinv[d]*(sum_{s in N(d)} hs[s,:] + hs[d,:]) + b) ----------
template <int C, int NY>
__global__ void agg4_kernel(const int* __restrict__ row_ptr, const int* __restrict__ deg,
                            const unsigned short* __restrict__ srcIdx, const float* __restrict__ hs,
                            const float* __restrict__ dinv, const float* __restrict__ b,
                            float* __restrict__ out, int n) {
    int tx = threadIdx.x;                               // [0, C/4)
    int d = blockIdx.x * NY + threadIdx.y;
    if (d >= n) return;
    int start = row_ptr[d];
    int cnt   = deg[d];
    float4 acc = *(const float4*)&hs[(long)d * C + tx * 4];   // self-loop term
    int k = 0;
    for (; k + 1 < cnt; k += 2) {
        int s0 = srcIdx[start + k];
        int s1 = srcIdx[start + k + 1];
        float4 v0 = *(const float4*)&hs[(long)s0 * C + tx * 4];
        float4 v1 = *(const float4*)&hs[(long)s1 * C + tx * 4];
        acc.x += v0.x + v1.x; acc.y += v0.y + v1.y;
        acc.z += v0.z + v1.z; acc.w += v0.w + v1.w;
    }
    if (k < cnt) {
        float4 v = *(const float4*)&hs[(long)srcIdx[start + k] * C + tx * 4];
        acc.x += v.x; acc.y += v.y; acc.z += v.z; acc.w += v.w;
    }
    float di = dinv[d];
    const float4 bb = *(const float4*)&b[tx * 4];
    float4 o;
    o.x = fmaxf(fmaf(di, acc.x, bb.x), 0.f);
    o.y = fmaxf(fmaf(di, acc.y, bb.y), 0.f);
    o.z = fmaxf(fmaf(di, acc.z, bb.z), 0.f);
    o.w = fmaxf(fmaf(di, acc.w, bb.w), 0.f);
    *(float4*)&out[(long)d * C + tx * 4] = o;
}

extern "C" void kernel_launch(void* const* d_in, const int* in_sizes, int n_in,
                              void* d_out, int out_size, void* d_ws, size_t ws_size,
                              hipStream_t stream) {
    const float* x  = (const float*)d_in[0];
    const int*   ei = (const int*)d_in[1];
    const float* W1 = (const float*)d_in[2];
    const float* b1 = (const float*)d_in[3];
    const float* W2 = (const float*)d_in[4];
    const float* b2 = (const float*)d_in[5];
    float* out = (float*)d_out;

    const int n = in_sizes[0] / D_IN;       // 50000
    const int E = in_sizes[1] / 2;          // 800000
    const int* srcp = ei;                   // edge_index[0]
    const int* dstp = ei + E;               // edge_index[1]

    // ws layout — NOTE: cursor spans [768KB, 768KB + n*4) ~= [768KB, 963.3KB).
    // Round-6 bug: partial/offs at 960/962KB sat INSIDE cursor -> scanC's
    // cursor writes raced with other blocks' offs reads (scheduling-dependent
    // output => tripwire). partial/offs now live past 968KB, clear of cursor.
    char* ws = (char*)d_ws;
    float* dinv   = (float*)(ws);
    int*   deg    = (int*)  (ws + (256u << 10));
    int*   rowp   = (int*)  (ws + (512u << 10));
    int*   cursor = (int*)  (ws + (768u << 10));
    int*   partial= (int*)  (ws + (968u << 10));         // 64 ints max
    int*   offs   = (int*)  (ws + (996u << 10));         // 64 ints max
    unsigned short* srcIdx = (unsigned short*)(ws + (1u << 20));  // E ushort = 1.6 MB
    float* h1s    = (float*)(ws + (5u << 20));
    float* act1   = (float*)(ws + (25u << 20));
    float* g2s    = h1s;                                 // dead by layer 2

    hipMemsetAsync(deg, 0, (size_t)n * sizeof(int), stream);

    const int nb = (n + CHUNK - 1) / CHUNK;              // 13

    // CSR build
    deg_kernel<<<(E / 4 + 255) / 256, 256, 0, stream>>>(dstp, deg, E);
    scanA_kernel<<<nb, 1024, 0, stream>>>(deg, partial, n);
    scanB_kernel<<<1, 64, 0, stream>>>(partial, offs, nb);
    scanC_kernel<<<nb, 1024, 0, stream>>>(deg, offs, rowp, cursor, dinv, n);
    fill_kernel<<<(E / 4 + 255) / 256, 256, 0, stream>>>(srcp, dstp, cursor, srcIdx, E);

    const int BM = 64;
    const int nblk = (n + BM - 1) / BM;

    // layer 1
    {
        dim3 blk(D_HID / 4, BM / 4);   // (24,16) = 384 threads
        gemm_tiled_kernel<D_IN, D_HID, BM><<<nblk, blk, 0, stream>>>(x, W1, dinv, h1s, n);
        dim3 ablk(D_HID / 4, 8);       // (24,8) = 192 threads
        agg4_kernel<D_HID, 8><<<(n + 7) / 8, ablk, 0, stream>>>(rowp, deg, srcIdx, h1s, dinv, b1, act1, n);
    }

    // layer 2
    {
        dim3 blk(D_OUT / 4, BM / 4);   // (16,16) = 256 threads
        gemm_tiled_kernel<D_HID, D_OUT, BM><<<nblk, blk, 0, stream>>>(act1, W2, dinv, g2s, n);
        dim3 ablk(D_OUT / 4, 16);      // (16,16) = 256 threads
        agg4_kernel<D_OUT, 16><<<(n + 15) / 16, ablk, 0, stream>>>(rowp, deg, srcIdx, g2s, dinv, b2, out, n);
    }
}

// Round 8
// 268.161 us; speedup vs baseline: 3.1927x; 1.0655x over previous
//
#include <hip/hip_runtime.h>

#define D_IN 128
#define D_HID 96
#define D_OUT 64
#define CHUNK 4096

// ================= fused: gemm1 (no dinv scale) | deg atomics =================
// Blocks [0, nblkGemm) compute H = X @ W (64-row tiles, KT=32, 4x4 reg tile).
// Blocks [nblkGemm, ...) count degrees (4 edges/thread, int atomics).
// The two halves are independent (inputs only) — co-residency hides the
// latency-bound atomics under the VALU-bound GEMM.
template <int K, int C, int BM>
__global__ void gemm1_deg_kernel(const float* __restrict__ X, const float* __restrict__ W,
                                 float* __restrict__ H, int n, int nblkGemm,
                                 const int* __restrict__ dst, int* __restrict__ deg, int E) {
    constexpr int KT = 32;
    constexpr int TX = C / 4;
    constexpr int TY = BM / 4;
    constexpr int NTH = TX * TY;
    constexpr int WS = C + 4;
    constexpr int XS = KT + 4;
    __shared__ float Wl[KT * WS];
    __shared__ float Xl[BM * XS];

    const int tx = threadIdx.x, ty = threadIdx.y;
    const int tlin = ty * TX + tx;

    if (blockIdx.x >= nblkGemm) {
        // ---- degree-count half ----
        int e0 = ((blockIdx.x - nblkGemm) * NTH + tlin) * 4;
        if (e0 + 3 < E) {
            int4 d = *(const int4*)&dst[e0];
            atomicAdd(&deg[d.x], 1);
            atomicAdd(&deg[d.y], 1);
            atomicAdd(&deg[d.z], 1);
            atomicAdd(&deg[d.w], 1);
        } else {
            for (int j = 0; j < 4; ++j) {
                int e = e0 + j;
                if (e < E) atomicAdd(&deg[dst[e]], 1);
            }
        }
        return;
    }

    // ---- GEMM half (KT=32 k-tiles; full unroll of KT>=64 spilled in round 3) ----
    const int r0 = blockIdx.x * BM;
    const int row0 = ty * 4;

    float4 acc0 = {0,0,0,0}, acc1 = {0,0,0,0}, acc2 = {0,0,0,0}, acc3 = {0,0,0,0};

    for (int kt0 = 0; kt0 < K; kt0 += KT) {
        for (int q = tlin; q < KT * (C / 4); q += NTH) {
            int k = q / (C / 4), cq = q % (C / 4);
            *(float4*)&Wl[k * WS + cq * 4] = *(const float4*)&W[(long)(kt0 + k) * C + cq * 4];
        }
        for (int q = tlin; q < BM * (KT / 4); q += NTH) {
            int r = q / (KT / 4), kq = q % (KT / 4);
            int gr = r0 + r; if (gr >= n) gr = n - 1;
            *(float4*)&Xl[r * XS + kq * 4] = *(const float4*)&X[(long)gr * K + kt0 + kq * 4];
        }
        __syncthreads();
#pragma unroll 4
        for (int k = 0; k < KT; ++k) {
            float4 w = *(const float4*)&Wl[k * WS + tx * 4];
            float x0 = Xl[(row0 + 0) * XS + k];
            float x1 = Xl[(row0 + 1) * XS + k];
            float x2 = Xl[(row0 + 2) * XS + k];
            float x3 = Xl[(row0 + 3) * XS + k];
            acc0.x = fmaf(x0, w.x, acc0.x); acc0.y = fmaf(x0, w.y, acc0.y);
            acc0.z = fmaf(x0, w.z, acc0.z); acc0.w = fmaf(x0, w.w, acc0.w);
            acc1.x = fmaf(x1, w.x, acc1.x); acc1.y = fmaf(x1, w.y, acc1.y);
            acc1.z = fmaf(x1, w.z, acc1.z); acc1.w = fmaf(x1, w.w, acc1.w);
            acc2.x = fmaf(x2, w.x, acc2.x); acc2.y = fmaf(x2, w.y, acc2.y);
            acc2.z = fmaf(x2, w.z, acc2.z); acc2.w = fmaf(x2, w.w, acc2.w);
            acc3.x = fmaf(x3, w.x, acc3.x); acc3.y = fmaf(x3, w.y, acc3.y);
            acc3.z = fmaf(x3, w.z, acc3.z); acc3.w = fmaf(x3, w.w, acc3.w);
        }
        __syncthreads();
    }

    float4 a[4] = {acc0, acc1, acc2, acc3};
#pragma unroll
    for (int i = 0; i < 4; ++i) {
        int row = r0 + row0 + i;
        if (row < n) *(float4*)&H[(long)row * C + tx * 4] = a[i];
    }
}

// ---------- scan pass A: per-chunk sums ----------
__global__ void scanA_kernel(const int* __restrict__ deg, int* __restrict__ partial, int n) {
    __shared__ int wsum[16];
    const int tid = threadIdx.x, lane = tid & 63, wid = tid >> 6;
    int i0 = blockIdx.x * CHUNK + tid * 4;
    int s = 0;
    if (i0 + 3 < n) {
        int4 v = *(const int4*)&deg[i0];
        s = v.x + v.y + v.z + v.w;
    } else {
        for (int j = 0; j < 4; ++j) if (i0 + j < n) s += deg[i0 + j];
    }
    for (int off = 32; off; off >>= 1) s += __shfl_down(s, off);
    if (lane == 0) wsum[wid] = s;
    __syncthreads();
    if (tid == 0) {
        int t = 0;
        for (int w = 0; w < 16; ++w) t += wsum[w];
        partial[blockIdx.x] = t;
    }
}

// ---------- scan pass B: exclusive scan of <=64 chunk sums ----------
__global__ void scanB_kernel(const int* __restrict__ partial, int* __restrict__ offs, int nb) {
    int lane = threadIdx.x;
    int v = (lane < nb) ? partial[lane] : 0;
    int s = v;
    for (int off = 1; off < 64; off <<= 1) {
        int t = __shfl_up(s, off);
        if (lane >= off) s += t;
    }
    if (lane < nb) offs[lane] = s - v;
}

// ---------- scan pass C: per-chunk scan + base; row_ptr/cursor/dinv ----------
__global__ void scanC_kernel(const int* __restrict__ deg, const int* __restrict__ offs,
                             int* __restrict__ row_ptr, int* __restrict__ cursor,
                             float* __restrict__ dinv, int n) {
    __shared__ int wsum[16];
    const int tid = threadIdx.x, lane = tid & 63, wid = tid >> 6;
    const int base = offs[blockIdx.x];
    int i0 = blockIdx.x * CHUNK + tid * 4;
    int v0 = (i0 + 0 < n) ? deg[i0 + 0] : 0;
    int v1 = (i0 + 1 < n) ? deg[i0 + 1] : 0;
    int v2 = (i0 + 2 < n) ? deg[i0 + 2] : 0;
    int v3 = (i0 + 3 < n) ? deg[i0 + 3] : 0;
    int p0 = v0, p1 = p0 + v1, p2 = p1 + v2, p3 = p2 + v3;
    int tsum = p3;
    for (int off = 1; off < 64; off <<= 1) {
        int t = __shfl_up(tsum, off);
        if (lane >= off) tsum += t;
    }
    if (lane == 63) wsum[wid] = tsum;
    __syncthreads();
    if (wid == 0) {
        int w = (lane < 16) ? wsum[lane] : 0;
        for (int off = 1; off < 16; off <<= 1) {
            int t = __shfl_up(w, off);
            if (lane >= off) w += t;
        }
        if (lane < 16) wsum[lane] = w;
    }
    __syncthreads();
    int texcl = base + (wid ? wsum[wid - 1] : 0) + tsum - p3;
    int e0 = texcl, e1 = texcl + p0, e2 = texcl + p1, e3 = texcl + p2;
    if (i0 + 0 < n) { row_ptr[i0+0] = e0; cursor[i0+0] = e0; dinv[i0+0] = rsqrtf((float)v0 + 1.0f); }
    if (i0 + 1 < n) { row_ptr[i0+1] = e1; cursor[i0+1] = e1; dinv[i0+1] = rsqrtf((float)v1 + 1.0f); }
    if (i0 + 2 < n) { row_ptr[i0+2] = e2; cursor[i0+2] = e2; dinv[i0+2] = rsqrtf((float)v2 + 1.0f); }
    if (i0 + 3 < n) { row_ptr[i0+3] = e3; cursor[i0+3] = e3; dinv[i0+3] = rsqrtf((float)v3 + 1.0f); }
}

// ---------- bucket src indices by dst; 4 edges/thread, ushort payload ----------
__global__ void fill_kernel(const int* __restrict__ src, const int* __restrict__ dst,
                            int* __restrict__ cursor, unsigned short* __restrict__ srcIdx, int E) {
    int e0 = (blockIdx.x * blockDim.x + threadIdx.x) * 4;
    if (e0 + 3 < E) {
        int4 d = *(const int4*)&dst[e0];
        int4 s = *(const int4*)&src[e0];
        int p0 = atomicAdd(&cursor[d.x], 1);
        int p1 = atomicAdd(&cursor[d.y], 1);
        int p2 = atomicAdd(&cursor[d.z], 1);
        int p3 = atomicAdd(&cursor[d.w], 1);
        srcIdx[p0] = (unsigned short)s.x;
        srcIdx[p1] = (unsigned short)s.y;
        srcIdx[p2] = (unsigned short)s.z;
        srcIdx[p3] = (unsigned short)s.w;
    } else {
        for (int j = 0; j < 4; ++j) {
            int e = e0 + j;
            if (e < E) {
                int pos = atomicAdd(&cursor[dst[e]], 1);
                srcIdx[pos] = (unsigned short)src[e];
            }
        }
    }
}

// ---------- tiled GEMM with dinv epilogue (layer 2) ----------
template <int K, int C, int BM>
__global__ void gemm_tiled_kernel(const float* __restrict__ X, const float* __restrict__ W,
                                  const float* __restrict__ dinv, float* __restrict__ H, int n) {
    constexpr int KT = 32;
    constexpr int TX = C / 4;
    constexpr int TY = BM / 4;
    constexpr int NTH = TX * TY;
    constexpr int WS = C + 4;
    constexpr int XS = KT + 4;
    __shared__ float Wl[KT * WS];
    __shared__ float Xl[BM * XS];

    const int tx = threadIdx.x, ty = threadIdx.y;
    const int tlin = ty * TX + tx;
    const int r0 = blockIdx.x * BM;
    const int row0 = ty * 4;

    float4 acc0 = {0,0,0,0}, acc1 = {0,0,0,0}, acc2 = {0,0,0,0}, acc3 = {0,0,0,0};

    for (int kt0 = 0; kt0 < K; kt0 += KT) {
        for (int q = tlin; q < KT * (C / 4); q += NTH) {
            int k = q / (C / 4), cq = q % (C / 4);
            *(float4*)&Wl[k * WS + cq * 4] = *(const float4*)&W[(long)(kt0 + k) * C + cq * 4];
        }
        for (int q = tlin; q < BM * (KT / 4); q += NTH) {
            int r = q / (KT / 4), kq = q % (KT / 4);
            int gr = r0 + r; if (gr >= n) gr = n - 1;
            *(float4*)&Xl[r * XS + kq * 4] = *(const float4*)&X[(long)gr * K + kt0 + kq * 4];
        }
        __syncthreads();
#pragma unroll 4
        for (int k = 0; k < KT; ++k) {
            float4 w = *(const float4*)&Wl[k * WS + tx * 4];
            float x0 = Xl[(row0 + 0) * XS + k];
            float x1 = Xl[(row0 + 1) * XS + k];
            float x2 = Xl[(row0 + 2) * XS + k];
            float x3 = Xl[(row0 + 3) * XS + k];
            acc0.x = fmaf(x0, w.x, acc0.x); acc0.y = fmaf(x0, w.y, acc0.y);
            acc0.z = fmaf(x0, w.z, acc0.z); acc0.w = fmaf(x0, w.w, acc0.w);
            acc1.x = fmaf(x1, w.x, acc1.x); acc1.y = fmaf(x1, w.y, acc1.y);
            acc1.z = fmaf(x1, w.z, acc1.z); acc1.w = fmaf(x1, w.w, acc1.w);
            acc2.x = fmaf(x2, w.x, acc2.x); acc2.y = fmaf(x2, w.y, acc2.y);
            acc2.z = fmaf(x2, w.z, acc2.z); acc2.w = fmaf(x2, w.w, acc2.w);
            acc3.x = fmaf(x3, w.x, acc3.x); acc3.y = fmaf(x3, w.y, acc3.y);
            acc3.z = fmaf(x3, w.z, acc3.z); acc3.w = fmaf(x3, w.w, acc3.w);
        }
        __syncthreads();
    }

    float4 a[4] = {acc0, acc1, acc2, acc3};
#pragma unroll
    for (int i = 0; i < 4; ++i) {
        int row = r0 + row0 + i;
        if (row < n) {
            float di = dinv[row];
            float4 o = {a[i].x * di, a[i].y * di, a[i].z * di, a[i].w * di};
            *(float4*)&H[(long)row * C + tx * 4] = o;
        }
    }
}

// ---------- aggregation + bias + ReLU ----------
// SCALE_SRC=true : hs holds raw h; gather applies dinv[s] (layer 1, unscaled gemm)
// SCALE_SRC=false: hs pre-scaled by dinv (layer 2)
// 4-deep unrolled gather for MLP on the latency-bound random reads.
template <int C, int NY, bool SCALE_SRC>
__global__ void agg4_kernel(const int* __restrict__ row_ptr, const int* __restrict__ deg,
                            const unsigned short* __restrict__ srcIdx, const float* __restrict__ hs,
                            const float* __restrict__ dinv, const float* __restrict__ b,
                            float* __restrict__ out, int n) {
    int tx = threadIdx.x;                               // [0, C/4)
    int d = blockIdx.x * NY + threadIdx.y;
    if (d >= n) return;
    int start = row_ptr[d];
    int cnt   = deg[d];
    float di  = dinv[d];
    float4 acc = *(const float4*)&hs[(long)d * C + tx * 4];   // self-loop term
    if (SCALE_SRC) { acc.x *= di; acc.y *= di; acc.z *= di; acc.w *= di; }
    int k = 0;
    for (; k + 3 < cnt; k += 4) {
        int s0 = srcIdx[start + k + 0];
        int s1 = srcIdx[start + k + 1];
        int s2 = srcIdx[start + k + 2];
        int s3 = srcIdx[start + k + 3];
        float4 v0 = *(const float4*)&hs[(long)s0 * C + tx * 4];
        float4 v1 = *(const float4*)&hs[(long)s1 * C + tx * 4];
        float4 v2 = *(const float4*)&hs[(long)s2 * C + tx * 4];
        float4 v3 = *(const float4*)&hs[(long)s3 * C + tx * 4];
        if (SCALE_SRC) {
            float n0 = dinv[s0], n1 = dinv[s1], n2 = dinv[s2], n3 = dinv[s3];
            acc.x = fmaf(v0.x, n0, acc.x); acc.y = fmaf(v0.y, n0, acc.y);
            acc.z = fmaf(v0.z, n0, acc.z); acc.w = fmaf(v0.w, n0, acc.w);
            acc.x = fmaf(v1.x, n1, acc.x); acc.y = fmaf(v1.y, n1, acc.y);
            acc.z = fmaf(v1.z, n1, acc.z); acc.w = fmaf(v1.w, n1, acc.w);
            acc.x = fmaf(v2.x, n2, acc.x); acc.y = fmaf(v2.y, n2, acc.y);
            acc.z = fmaf(v2.z, n2, acc.z); acc.w = fmaf(v2.w, n2, acc.w);
            acc.x = fmaf(v3.x, n3, acc.x); acc.y = fmaf(v3.y, n3, acc.y);
            acc.z = fmaf(v3.z, n3, acc.z); acc.w = fmaf(v3.w, n3, acc.w);
        } else {
            acc.x += v0.x + v1.x + v2.x + v3.x;
            acc.y += v0.y + v1.y + v2.y + v3.y;
            acc.z += v0.z + v1.z + v2.z + v3.z;
            acc.w += v0.w + v1.w + v2.w + v3.w;
        }
    }
    for (; k < cnt; ++k) {
        int s = srcIdx[start + k];
        float4 v = *(const float4*)&hs[(long)s * C + tx * 4];
        if (SCALE_SRC) {
            float nm = dinv[s];
            acc.x = fmaf(v.x, nm, acc.x); acc.y = fmaf(v.y, nm, acc.y);
            acc.z = fmaf(v.z, nm, acc.z); acc.w = fmaf(v.w, nm, acc.w);
        } else {
            acc.x += v.x; acc.y += v.y; acc.z += v.z; acc.w += v.w;
        }
    }
    const float4 bb = *(const float4*)&b[tx * 4];
    float4 o;
    o.x = fmaxf(fmaf(di, acc.x, bb.x), 0.f);
    o.y = fmaxf(fmaf(di, acc.y, bb.y), 0.f);
    o.z = fmaxf(fmaf(di, acc.z, bb.z), 0.f);
    o.w = fmaxf(fmaf(di, acc.w, bb.w), 0.f);
    *(float4*)&out[(long)d * C + tx * 4] = o;
}

extern "C" void kernel_launch(void* const* d_in, const int* in_sizes, int n_in,
                              void* d_out, int out_size, void* d_ws, size_t ws_size,
                              hipStream_t stream) {
    const float* x  = (const float*)d_in[0];
    const int*   ei = (const int*)d_in[1];
    const float* W1 = (const float*)d_in[2];
    const float* b1 = (const float*)d_in[3];
    const float* W2 = (const float*)d_in[4];
    const float* b2 = (const float*)d_in[5];
    float* out = (float*)d_out;

    const int n = in_sizes[0] / D_IN;       // 50000
    const int E = in_sizes[1] / 2;          // 800000
    const int* srcp = ei;                   // edge_index[0]
    const int* dstp = ei + E;               // edge_index[1]

    // ws layout — cursor spans [768KB, ~963.3KB); partial/offs live past it
    // (round-6 lesson: overlap with cursor raced => tripwire).
    char* ws = (char*)d_ws;
    float* dinv   = (float*)(ws);
    int*   deg    = (int*)  (ws + (256u << 10));
    int*   rowp   = (int*)  (ws + (512u << 10));
    int*   cursor = (int*)  (ws + (768u << 10));
    int*   partial= (int*)  (ws + (968u << 10));
    int*   offs   = (int*)  (ws + (996u << 10));
    unsigned short* srcIdx = (unsigned short*)(ws + (1u << 20));
    float* h1     = (float*)(ws + (5u << 20));           // raw h1 (unscaled)
    float* act1   = (float*)(ws + (25u << 20));
    float* g2s    = h1;                                  // dead by layer 2

    hipMemsetAsync(deg, 0, (size_t)n * sizeof(int), stream);

    const int nb = (n + CHUNK - 1) / CHUNK;              // 13
    const int BM = 64;
    const int nblk = (n + BM - 1) / BM;                  // 782

    // K1: fused gemm1 | deg.  gemm half: (24,16)=384 thr; deg half: 521 blocks.
    {
        const int degBlocks = (E / 4 + 383) / 384;
        dim3 blk(D_HID / 4, BM / 4);
        gemm1_deg_kernel<D_IN, D_HID, BM><<<nblk + degBlocks, blk, 0, stream>>>(
            x, W1, h1, n, nblk, dstp, deg, E);
    }

    // CSR scan + fill
    scanA_kernel<<<nb, 1024, 0, stream>>>(deg, partial, n);
    scanB_kernel<<<1, 64, 0, stream>>>(partial, offs, nb);
    scanC_kernel<<<nb, 1024, 0, stream>>>(deg, offs, rowp, cursor, dinv, n);
    fill_kernel<<<(E / 4 + 255) / 256, 256, 0, stream>>>(srcp, dstp, cursor, srcIdx, E);

    // layer 1 aggregation: applies dinv[s] at gather (h1 is unscaled)
    {
        dim3 ablk(D_HID / 4, 8);       // (24,8) = 192 threads
        agg4_kernel<D_HID, 8, true><<<(n + 7) / 8, ablk, 0, stream>>>(
            rowp, deg, srcIdx, h1, dinv, b1, act1, n);
    }

    // layer 2
    {
        dim3 blk(D_OUT / 4, BM / 4);   // (16,16) = 256 threads
        gemm_tiled_kernel<D_HID, D_OUT, BM><<<nblk, blk, 0, stream>>>(act1, W2, dinv, g2s, n);
        dim3 ablk(D_OUT / 4, 16);      // (16,16) = 256 threads
        agg4_kernel<D_OUT, 16, false><<<(n + 15) / 16, ablk, 0, stream>>>(
            rowp, deg, srcIdx, g2s, dinv, b2, out, n);
    }
}